// Round 3
// baseline (312.133 us; speedup 1.0000x reference)
//
#include <hip/hip_runtime.h>
#include <stdint.h>

typedef unsigned short u16;
typedef short s16x8 __attribute__((ext_vector_type(8)));
typedef float f32x4 __attribute__((ext_vector_type(4)));

#define LOG2E 1.44269504088896340736f

constexpr int Bc = 2, Sc = 4096, Ec = 768, Hc = 12;
constexpr int Mrows = Bc * Sc; // 8192

__device__ __forceinline__ u16 f2b(float x) {
  union { float f; uint32_t u; } v; v.f = x;
  return (u16)((v.u + 0x7FFFu + ((v.u >> 16) & 1u)) >> 16);
}

__device__ __forceinline__ void gld16(const u16* g, u16* l) {
  __builtin_amdgcn_global_load_lds(
      (const __attribute__((address_space(1))) void*)g,
      (__attribute__((address_space(3))) void*)l,
      16, 0, 0);
}

// ---------------- convert hs f32 -> bf16 ----------------
__global__ void k_cvt(const float* __restrict__ in, u16* __restrict__ out, int n) {
  int i = (blockIdx.x * blockDim.x + threadIdx.x) * 4;
  if (i >= n) return;
  const float4 v = *reinterpret_cast<const float4*>(in + i);
  ushort4 o;
  o.x = f2b(v.x); o.y = f2b(v.y); o.z = f2b(v.z); o.w = f2b(v.w);
  *reinterpret_cast<ushort4*>(out + i) = o;
}

// ---------------- transpose + convert: out[c][r] = bf16(in[r][c]) ----------------
__global__ void k_tcvt(const float* __restrict__ in, u16* __restrict__ out, int RR, int CC) {
  __shared__ float t[32][33];
  const int c0 = blockIdx.x * 32, r0 = blockIdx.y * 32;
  const int tx = threadIdx.x, ty = threadIdx.y;
#pragma unroll
  for (int i = 0; i < 32; i += 8)
    t[ty + i][tx] = in[(size_t)(r0 + ty + i) * CC + c0 + tx];
  __syncthreads();
#pragma unroll
  for (int i = 0; i < 32; i += 8)
    out[(size_t)(c0 + ty + i) * RR + r0 + tx] = f2b(t[tx][ty + i]);
}

// ---------------- QKV GEMM: A[8192x768] @ Bt[2304x768]^T, scatter epilogue ----------------
// 1D grid, XCD-swizzled: each XCD owns an 8-M-tile slice (A-slice 1.5 MB, L2-resident).
__global__ __launch_bounds__(256) void k_gemm_qkv(
    const u16* __restrict__ A, const u16* __restrict__ Bt,
    const float* __restrict__ bq, const float* __restrict__ bk, const float* __restrict__ bv,
    u16* __restrict__ q_ws, u16* __restrict__ k_ws, u16* __restrict__ vt_ws) {
  __shared__ __align__(16) u16 As[128 * 64];
  __shared__ __align__(16) u16 Bs[128 * 64];
  const int bid = blockIdx.x;
  const int xcd = bid & 7, ii = bid >> 3;          // ii in 0..143
  const int m0 = (xcd * 8 + (ii & 7)) * 128;       // 64 M-tiles
  const int n0 = (ii >> 3) * 128;                  // 18 N-tiles
  const int tid = threadIdx.x;
  const int lane = tid & 63, w = tid >> 6;
  const int wm = w >> 1, wn = w & 1;
  const int lr = lane & 15, lg = lane >> 4;

  f32x4 acc[4][4] = {};
  const int fl0 = lane * 8;

  for (int k0 = 0; k0 < Ec; k0 += 64) {
#pragma unroll
    for (int c = 0; c < 4; ++c) {
      const int f = (w * 4 + c) * 512;
      const int fl = f + fl0;
      const int row = fl >> 6, col = fl & 63;
      gld16(A + (size_t)(m0 + row) * Ec + k0 + col, &As[f]);
      gld16(Bt + (size_t)(n0 + row) * Ec + k0 + col, &Bs[f]);
    }
    __syncthreads();
    s16x8 af[4][2], bf[4][2];
#pragma unroll
    for (int i = 0; i < 4; ++i) {
#pragma unroll
      for (int ks = 0; ks < 2; ++ks) {
        af[i][ks] = *reinterpret_cast<const s16x8*>(&As[(wm * 64 + i * 16 + lr) * 64 + ks * 32 + lg * 8]);
        bf[i][ks] = *reinterpret_cast<const s16x8*>(&Bs[(wn * 64 + i * 16 + lr) * 64 + ks * 32 + lg * 8]);
      }
    }
#pragma unroll
    for (int mf = 0; mf < 4; ++mf)
#pragma unroll
      for (int nf = 0; nf < 4; ++nf) {
        acc[mf][nf] = __builtin_amdgcn_mfma_f32_16x16x32_bf16(af[mf][0], bf[nf][0], acc[mf][nf], 0, 0, 0);
        acc[mf][nf] = __builtin_amdgcn_mfma_f32_16x16x32_bf16(af[mf][1], bf[nf][1], acc[mf][nf], 0, 0, 0);
      }
    __syncthreads();
  }

  const int which = n0 / Ec; // 0=q 1=k 2=v, uniform per block
#pragma unroll
  for (int nf = 0; nf < 4; ++nf) {
    const int ng = n0 + wn * 64 + nf * 16 + lr;
    const int nl = ng - which * Ec;
    const int hh = nl >> 6, dd = nl & 63;
    const float bias = (which == 0 ? bq[nl] : which == 1 ? bk[nl] : bv[nl]);
#pragma unroll
    for (int mf = 0; mf < 4; ++mf) {
      const int mg = m0 + wm * 64 + mf * 16 + lg * 4;
      const int bb = mg >> 12, ss = mg & (Sc - 1);
      const int bh = bb * Hc + hh;
      if (which == 2) {
        ushort4 pk;
        pk.x = f2b(acc[mf][nf][0] + bias);
        pk.y = f2b(acc[mf][nf][1] + bias);
        pk.z = f2b(acc[mf][nf][2] + bias);
        pk.w = f2b(acc[mf][nf][3] + bias);
        *reinterpret_cast<ushort4*>(&vt_ws[((size_t)bh * 64 + dd) * Sc + ss]) = pk;
      } else {
        u16* dst = (which == 0) ? q_ws : k_ws;
        const float scl = (which == 0) ? 0.125f : 1.0f;
#pragma unroll
        for (int r = 0; r < 4; ++r)
          dst[((size_t)bh * Sc + ss + r) * 64 + dd] = f2b((acc[mf][nf][r] + bias) * scl);
      }
    }
  }
}

// ---------------- output GEMM: ctx[8192x768] @ Wo^T[768x768], +bo, f32 out ----------------
__global__ __launch_bounds__(256) void k_gemm_out(
    const u16* __restrict__ A, const u16* __restrict__ Bt,
    const float* __restrict__ bo, float* __restrict__ out) {
  __shared__ __align__(16) u16 As[128 * 64];
  __shared__ __align__(16) u16 Bs[128 * 64];
  const int bid = blockIdx.x;
  const int xcd = bid & 7, ii = bid >> 3;          // ii in 0..47
  const int m0 = (xcd * 8 + (ii & 7)) * 128;
  const int n0 = (ii >> 3) * 128;                  // 6 N-tiles
  const int tid = threadIdx.x;
  const int lane = tid & 63, w = tid >> 6;
  const int wm = w >> 1, wn = w & 1;
  const int lr = lane & 15, lg = lane >> 4;

  f32x4 acc[4][4] = {};
  const int fl0 = lane * 8;

  for (int k0 = 0; k0 < Ec; k0 += 64) {
#pragma unroll
    for (int c = 0; c < 4; ++c) {
      const int f = (w * 4 + c) * 512;
      const int fl = f + fl0;
      const int row = fl >> 6, col = fl & 63;
      gld16(A + (size_t)(m0 + row) * Ec + k0 + col, &As[f]);
      gld16(Bt + (size_t)(n0 + row) * Ec + k0 + col, &Bs[f]);
    }
    __syncthreads();
    s16x8 af[4][2], bf[4][2];
#pragma unroll
    for (int i = 0; i < 4; ++i) {
#pragma unroll
      for (int ks = 0; ks < 2; ++ks) {
        af[i][ks] = *reinterpret_cast<const s16x8*>(&As[(wm * 64 + i * 16 + lr) * 64 + ks * 32 + lg * 8]);
        bf[i][ks] = *reinterpret_cast<const s16x8*>(&Bs[(wn * 64 + i * 16 + lr) * 64 + ks * 32 + lg * 8]);
      }
    }
#pragma unroll
    for (int mf = 0; mf < 4; ++mf)
#pragma unroll
      for (int nf = 0; nf < 4; ++nf) {
        acc[mf][nf] = __builtin_amdgcn_mfma_f32_16x16x32_bf16(af[mf][0], bf[nf][0], acc[mf][nf], 0, 0, 0);
        acc[mf][nf] = __builtin_amdgcn_mfma_f32_16x16x32_bf16(af[mf][1], bf[nf][1], acc[mf][nf], 0, 0, 0);
      }
    __syncthreads();
  }

#pragma unroll
  for (int nf = 0; nf < 4; ++nf) {
    const int ng = n0 + wn * 64 + nf * 16 + lr;
    const float bias = bo[ng];
#pragma unroll
    for (int mf = 0; mf < 4; ++mf) {
      const int mg = m0 + wm * 64 + mf * 16 + lg * 4;
#pragma unroll
      for (int r = 0; r < 4; ++r)
        out[(size_t)(mg + r) * Ec + ng] = acc[mf][nf][r] + bias;
    }
  }
}

// ---------------- local attention (swapped-QK, per-lane softmax) ----------------
// One wave per block (64 thr), 6144 blocks, XCD-swizzled: each XCD owns 3 bh
// slices (K+V 3 MB -> L2). QK computed as mfma(K,Q): lane holds 16 scores of
// query q=lr -> softmax = in-lane reduce + 2 shfls. P repacked via
// v_cvt_pk_bf16_f32 + 4x ds_write_b64, read back as PV A-fragments.
__global__ __launch_bounds__(64, 4) void k_attn(
    const u16* __restrict__ q_ws, const u16* __restrict__ k_ws,
    const u16* __restrict__ vt_ws, u16* __restrict__ ctx_ws) {
  __shared__ __align__(16) u16 P[16 * 72]; // stride 72 u16 = 144 B (16B-aligned rows, ~2-way banks)
  const int lin = blockIdx.x;
  const int work = (lin & 7) * 768 + (lin >> 3); // bijective XCD swizzle (6144 % 8 == 0)
  const int bh = work >> 8;
  const int chunk = (work >> 2) & 63;
  const int w = work & 3;
  const int b = bh / Hc, h = bh - b * Hc;
  const int lane = threadIdx.x & 63;
  const int lr = lane & 15, lg = lane >> 4;

  const u16* qb = q_ws + (size_t)bh * Sc * 64;
  const u16* kb = k_ws + (size_t)bh * Sc * 64;
  const u16* vb = vt_ws + (size_t)bh * 64 * Sc;

  // Q as B-fragment: n = query = lr (same addresses as before)
  const int qrow = chunk * 64 + w * 16 + lr;
  const s16x8 qf0 = *reinterpret_cast<const s16x8*>(&qb[(size_t)qrow * 64 + lg * 8]);
  const s16x8 qf1 = *reinterpret_cast<const s16x8*>(&qb[(size_t)qrow * 64 + 32 + lg * 8]);

  float mrow = -3e38f;  // running max of query lr
  float ssum = 0.f;     // per-lane partial denominator (this lane's key subset)
  f32x4 ctx[4] = {};

  const int t0 = chunk < 4 ? 4 - chunk : 0;
  const int t1 = chunk > 59 ? 68 - chunk : 9;

  auto loadK = [&](s16x8 (&kf)[4][2], int t) {
    const int key0 = (chunk - 4 + t) * 64;
#pragma unroll
    for (int nt = 0; nt < 4; ++nt) {
      const u16* kp = &kb[(size_t)(key0 + nt * 16 + lr) * 64 + lg * 8];
      kf[nt][0] = *reinterpret_cast<const s16x8*>(kp);
      kf[nt][1] = *reinterpret_cast<const s16x8*>(kp + 32);
    }
  };

  auto step = [&](s16x8 (&kf)[4][2], s16x8 (&kn)[4][2], int t) {
    const int key0 = (chunk - 4 + t) * 64;
    // S^T = K Q^T: sv[nt][r] = S[key=nt*16+lg*4+r][query=lr]
    f32x4 sv[4];
    __builtin_amdgcn_s_setprio(1);
#pragma unroll
    for (int nt = 0; nt < 4; ++nt) {
      f32x4 z = {};
      z = __builtin_amdgcn_mfma_f32_16x16x32_bf16(kf[nt][0], qf0, z, 0, 0, 0);
      z = __builtin_amdgcn_mfma_f32_16x16x32_bf16(kf[nt][1], qf1, z, 0, 0, 0);
      sv[nt] = z;
    }
    __builtin_amdgcn_s_setprio(0);
    // prefetch next K tile (hidden under softmax+PV)
    if (t + 1 < t1) loadK(kn, t + 1);
    // issue V loads now; latency hides under the softmax chain
    s16x8 vf[4][2];
#pragma unroll
    for (int nt = 0; nt < 4; ++nt) {
      const u16* vp = &vb[(size_t)(nt * 16 + lr) * Sc + key0 + lg * 8];
      vf[nt][0] = *reinterpret_cast<const s16x8*>(vp);
      vf[nt][1] = *reinterpret_cast<const s16x8*>(vp + 32);
    }
    // ---- per-lane softmax for query lr ----
    float pm;
    {
      f32x4 m4 = sv[0];
      m4 = {fmaxf(m4[0], sv[1][0]), fmaxf(m4[1], sv[1][1]), fmaxf(m4[2], sv[1][2]), fmaxf(m4[3], sv[1][3])};
      m4 = {fmaxf(m4[0], sv[2][0]), fmaxf(m4[1], sv[2][1]), fmaxf(m4[2], sv[2][2]), fmaxf(m4[3], sv[2][3])};
      m4 = {fmaxf(m4[0], sv[3][0]), fmaxf(m4[1], sv[3][1]), fmaxf(m4[2], sv[3][2]), fmaxf(m4[3], sv[3][3])};
      pm = fmaxf(fmaxf(m4[0], m4[1]), fmaxf(m4[2], m4[3]));
    }
    pm = fmaxf(pm, __shfl_xor(pm, 16));
    pm = fmaxf(pm, __shfl_xor(pm, 32));
    // defer-max (T13): skip rescale while tile max stays within THR of running max
    if (!__all(pm <= mrow + 5.0f)) {
      const float mn = fmaxf(mrow, pm);
      const float scl = exp2f((mrow - mn) * LOG2E);
      ssum *= scl;
      float sc[4];
#pragma unroll
      for (int r = 0; r < 4; ++r) sc[r] = __shfl(scl, (lg << 2) | r); // ctx query = lg*4+r
#pragma unroll
      for (int nt = 0; nt < 4; ++nt)
#pragma unroll
        for (int r = 0; r < 4; ++r) ctx[nt][r] *= sc[r];
      mrow = mn;
    }
    const float ml2e = mrow * LOG2E;
    float ps = 0.f;
    uint32_t pk[4][2];
#pragma unroll
    for (int nt = 0; nt < 4; ++nt) {
      const float p0 = exp2f(sv[nt][0] * LOG2E - ml2e);
      const float p1 = exp2f(sv[nt][1] * LOG2E - ml2e);
      const float p2 = exp2f(sv[nt][2] * LOG2E - ml2e);
      const float p3 = exp2f(sv[nt][3] * LOG2E - ml2e);
      ps += (p0 + p1) + (p2 + p3);
      asm("v_cvt_pk_bf16_f32 %0, %1, %2" : "=v"(pk[nt][0]) : "v"(p0), "v"(p1));
      asm("v_cvt_pk_bf16_f32 %0, %1, %2" : "=v"(pk[nt][1]) : "v"(p2), "v"(p3));
    }
    ssum += ps;
    // P[q=lr][key]: 4 consecutive u16 per (nt) -> b64 writes
#pragma unroll
    for (int nt = 0; nt < 4; ++nt) {
      uint2 d; d.x = pk[nt][0]; d.y = pk[nt][1];
      *reinterpret_cast<uint2*>(&P[lr * 72 + nt * 16 + lg * 4]) = d;
    }
    // wave-local write->read ordering (guide rule #18)
    asm volatile("s_waitcnt lgkmcnt(0)" ::: "memory");
    __builtin_amdgcn_sched_barrier(0);
    // PV A-fragment: A[m=q=lr][k=key=lg*8..+7]
    const s16x8 pa0 = *reinterpret_cast<const s16x8*>(&P[lr * 72 + lg * 8]);
    const s16x8 pa1 = *reinterpret_cast<const s16x8*>(&P[lr * 72 + 32 + lg * 8]);
    __builtin_amdgcn_s_setprio(1);
#pragma unroll
    for (int nt = 0; nt < 4; ++nt) {
      ctx[nt] = __builtin_amdgcn_mfma_f32_16x16x32_bf16(pa0, vf[nt][0], ctx[nt], 0, 0, 0);
      ctx[nt] = __builtin_amdgcn_mfma_f32_16x16x32_bf16(pa1, vf[nt][1], ctx[nt], 0, 0, 0);
    }
    __builtin_amdgcn_s_setprio(0);
  };

  s16x8 kfA[4][2], kfB[4][2];
  loadK(kfA, t0);
  for (int t = t0; t < t1; ++t) {
    if (((t - t0) & 1) == 0) step(kfA, kfB, t); // uniform parity -> static reg indexing
    else step(kfB, kfA, t);
  }

  // finish denominator: sum per-lane partials across the 4 lg copies of query lr
  float s = ssum;
  s += __shfl_xor(s, 16);
  s += __shfl_xor(s, 32);
  const float invq = 1.f / s;
  float ic[4];
#pragma unroll
  for (int r = 0; r < 4; ++r) ic[r] = __shfl(invq, (lg << 2) | r); // ctx query = lg*4+r

  const int tok = chunk * 64 + w * 16 + lg * 4;
#pragma unroll
  for (int nt = 0; nt < 4; ++nt) {
    const int col = h * 64 + nt * 16 + lr;
#pragma unroll
    for (int r = 0; r < 4; ++r)
      ctx_ws[(size_t)(b * Sc + tok + r) * Ec + col] = f2b(ctx[nt][r] * ic[r]);
  }
}

extern "C" void kernel_launch(void* const* d_in, const int* in_sizes, int n_in,
                              void* d_out, int out_size, void* d_ws, size_t ws_size,
                              hipStream_t stream) {
  const float* hs = (const float*)d_in[0];
  const float* Wq = (const float*)d_in[1];
  const float* bq = (const float*)d_in[2];
  const float* Wk = (const float*)d_in[3];
  const float* bk = (const float*)d_in[4];
  const float* Wv = (const float*)d_in[5];
  const float* bv = (const float*)d_in[6];
  const float* Wo = (const float*)d_in[7];
  const float* bo = (const float*)d_in[8];
  float* out = (float*)d_out;

  char* ws = (char*)d_ws;
  size_t o = 0;
  u16* hsb = (u16*)(ws + o);   o += (size_t)Mrows * Ec * 2;
  u16* wqkvt = (u16*)(ws + o); o += (size_t)3 * Ec * Ec * 2;
  u16* wot = (u16*)(ws + o);   o += (size_t)Ec * Ec * 2;
  u16* q_ws = (u16*)(ws + o);  o += (size_t)Mrows * Ec * 2;      // [b,h,s,d]
  u16* k_ws = (u16*)(ws + o);  o += (size_t)Mrows * Ec * 2;      // [b,h,s,d]
  u16* vt_ws = (u16*)(ws + o); o += (size_t)Mrows * Ec * 2;      // [b,h,d,s]
  u16* ctx_ws = (u16*)(ws + o); o += (size_t)Mrows * Ec * 2;     // [b*s, e]

  const int nhs = Mrows * Ec;
  k_cvt<<<nhs / (256 * 4), 256, 0, stream>>>(hs, hsb, nhs);
  dim3 tb(32, 8);
  dim3 tg(Ec / 32, Ec / 32);
  k_tcvt<<<tg, tb, 0, stream>>>(Wq, wqkvt, Ec, Ec);
  k_tcvt<<<tg, tb, 0, stream>>>(Wk, wqkvt + (size_t)Ec * Ec, Ec, Ec);
  k_tcvt<<<tg, tb, 0, stream>>>(Wv, wqkvt + (size_t)2 * Ec * Ec, Ec, Ec);
  k_tcvt<<<tg, tb, 0, stream>>>(Wo, wot, Ec, Ec);

  k_gemm_qkv<<<1152, 256, 0, stream>>>(hsb, wqkvt, bq, bk, bv, q_ws, k_ws, vt_ws);

  k_attn<<<6144, 64, 0, stream>>>(q_ws, k_ws, vt_ws, ctx_ws);

  k_gemm_out<<<384, 256, 0, stream>>>(ctx_ws, wot, bo, out);
}

// Round 4
// 204.592 us; speedup vs baseline: 1.5256x; 1.5256x over previous
//
#include <hip/hip_runtime.h>
#include <stdint.h>

typedef unsigned short u16;
typedef short s16x8 __attribute__((ext_vector_type(8)));
typedef float f32x4 __attribute__((ext_vector_type(4)));

#define LOG2E 1.44269504088896340736f

constexpr int Bc = 2, Sc = 4096, Ec = 768, Hc = 12;
constexpr int Mrows = Bc * Sc; // 8192

__device__ __forceinline__ u16 f2b(float x) {
  union { float f; uint32_t u; } v; v.f = x;
  return (u16)((v.u + 0x7FFFu + ((v.u >> 16) & 1u)) >> 16);
}

__device__ __forceinline__ void gld16(const u16* g, u16* l) {
  __builtin_amdgcn_global_load_lds(
      (const __attribute__((address_space(1))) void*)g,
      (__attribute__((address_space(3))) void*)l,
      16, 0, 0);
}

// ---------------- convert hs f32 -> bf16 ----------------
__global__ void k_cvt(const float* __restrict__ in, u16* __restrict__ out, int n) {
  int i = (blockIdx.x * blockDim.x + threadIdx.x) * 4;
  if (i >= n) return;
  const float4 v = *reinterpret_cast<const float4*>(in + i);
  ushort4 o;
  o.x = f2b(v.x); o.y = f2b(v.y); o.z = f2b(v.z); o.w = f2b(v.w);
  *reinterpret_cast<ushort4*>(out + i) = o;
}

// ---------------- transpose + convert: out[c][r] = bf16(in[r][c]) ----------------
__global__ void k_tcvt(const float* __restrict__ in, u16* __restrict__ out, int RR, int CC) {
  __shared__ float t[32][33];
  const int c0 = blockIdx.x * 32, r0 = blockIdx.y * 32;
  const int tx = threadIdx.x, ty = threadIdx.y;
#pragma unroll
  for (int i = 0; i < 32; i += 8)
    t[ty + i][tx] = in[(size_t)(r0 + ty + i) * CC + c0 + tx];
  __syncthreads();
#pragma unroll
  for (int i = 0; i < 32; i += 8)
    out[(size_t)(c0 + ty + i) * RR + r0 + tx] = f2b(t[tx][ty + i]);
}

// ---------------- QKV GEMM: A[8192x768] @ Bt[2304x768]^T, scatter epilogue ----------------
// 1D grid, XCD-swizzled: each XCD owns an 8-M-tile slice (A-slice 1.5 MB, L2-resident).
__global__ __launch_bounds__(256) void k_gemm_qkv(
    const u16* __restrict__ A, const u16* __restrict__ Bt,
    const float* __restrict__ bq, const float* __restrict__ bk, const float* __restrict__ bv,
    u16* __restrict__ q_ws, u16* __restrict__ k_ws, u16* __restrict__ vt_ws) {
  __shared__ __align__(16) u16 As[128 * 64];
  __shared__ __align__(16) u16 Bs[128 * 64];
  const int bid = blockIdx.x;
  const int xcd = bid & 7, ii = bid >> 3;          // ii in 0..143
  const int m0 = (xcd * 8 + (ii & 7)) * 128;       // 64 M-tiles
  const int n0 = (ii >> 3) * 128;                  // 18 N-tiles
  const int tid = threadIdx.x;
  const int lane = tid & 63, w = tid >> 6;
  const int wm = w >> 1, wn = w & 1;
  const int lr = lane & 15, lg = lane >> 4;

  f32x4 acc[4][4] = {};
  const int fl0 = lane * 8;

  for (int k0 = 0; k0 < Ec; k0 += 64) {
#pragma unroll
    for (int c = 0; c < 4; ++c) {
      const int f = (w * 4 + c) * 512;
      const int fl = f + fl0;
      const int row = fl >> 6, col = fl & 63;
      gld16(A + (size_t)(m0 + row) * Ec + k0 + col, &As[f]);
      gld16(Bt + (size_t)(n0 + row) * Ec + k0 + col, &Bs[f]);
    }
    __syncthreads();
    s16x8 af[4][2], bf[4][2];
#pragma unroll
    for (int i = 0; i < 4; ++i) {
#pragma unroll
      for (int ks = 0; ks < 2; ++ks) {
        af[i][ks] = *reinterpret_cast<const s16x8*>(&As[(wm * 64 + i * 16 + lr) * 64 + ks * 32 + lg * 8]);
        bf[i][ks] = *reinterpret_cast<const s16x8*>(&Bs[(wn * 64 + i * 16 + lr) * 64 + ks * 32 + lg * 8]);
      }
    }
#pragma unroll
    for (int mf = 0; mf < 4; ++mf)
#pragma unroll
      for (int nf = 0; nf < 4; ++nf) {
        acc[mf][nf] = __builtin_amdgcn_mfma_f32_16x16x32_bf16(af[mf][0], bf[nf][0], acc[mf][nf], 0, 0, 0);
        acc[mf][nf] = __builtin_amdgcn_mfma_f32_16x16x32_bf16(af[mf][1], bf[nf][1], acc[mf][nf], 0, 0, 0);
      }
    __syncthreads();
  }

  const int which = n0 / Ec; // 0=q 1=k 2=v, uniform per block
#pragma unroll
  for (int nf = 0; nf < 4; ++nf) {
    const int ng = n0 + wn * 64 + nf * 16 + lr;
    const int nl = ng - which * Ec;
    const int hh = nl >> 6, dd = nl & 63;
    const float bias = (which == 0 ? bq[nl] : which == 1 ? bk[nl] : bv[nl]);
#pragma unroll
    for (int mf = 0; mf < 4; ++mf) {
      const int mg = m0 + wm * 64 + mf * 16 + lg * 4;
      const int bb = mg >> 12, ss = mg & (Sc - 1);
      const int bh = bb * Hc + hh;
      if (which == 2) {
        ushort4 pk;
        pk.x = f2b(acc[mf][nf][0] + bias);
        pk.y = f2b(acc[mf][nf][1] + bias);
        pk.z = f2b(acc[mf][nf][2] + bias);
        pk.w = f2b(acc[mf][nf][3] + bias);
        *reinterpret_cast<ushort4*>(&vt_ws[((size_t)bh * 64 + dd) * Sc + ss]) = pk;
      } else {
        u16* dst = (which == 0) ? q_ws : k_ws;
        const float scl = (which == 0) ? 0.125f : 1.0f;
#pragma unroll
        for (int r = 0; r < 4; ++r)
          dst[((size_t)bh * Sc + ss + r) * 64 + dd] = f2b((acc[mf][nf][r] + bias) * scl);
      }
    }
  }
}

// ---------------- output GEMM: ctx[8192x768] @ Wo^T[768x768], +bo, f32 out ----------------
__global__ __launch_bounds__(256) void k_gemm_out(
    const u16* __restrict__ A, const u16* __restrict__ Bt,
    const float* __restrict__ bo, float* __restrict__ out) {
  __shared__ __align__(16) u16 As[128 * 64];
  __shared__ __align__(16) u16 Bs[128 * 64];
  const int bid = blockIdx.x;
  const int xcd = bid & 7, ii = bid >> 3;          // ii in 0..47
  const int m0 = (xcd * 8 + (ii & 7)) * 128;
  const int n0 = (ii >> 3) * 128;                  // 6 N-tiles
  const int tid = threadIdx.x;
  const int lane = tid & 63, w = tid >> 6;
  const int wm = w >> 1, wn = w & 1;
  const int lr = lane & 15, lg = lane >> 4;

  f32x4 acc[4][4] = {};
  const int fl0 = lane * 8;

  for (int k0 = 0; k0 < Ec; k0 += 64) {
#pragma unroll
    for (int c = 0; c < 4; ++c) {
      const int f = (w * 4 + c) * 512;
      const int fl = f + fl0;
      const int row = fl >> 6, col = fl & 63;
      gld16(A + (size_t)(m0 + row) * Ec + k0 + col, &As[f]);
      gld16(Bt + (size_t)(n0 + row) * Ec + k0 + col, &Bs[f]);
    }
    __syncthreads();
    s16x8 af[4][2], bf[4][2];
#pragma unroll
    for (int i = 0; i < 4; ++i) {
#pragma unroll
      for (int ks = 0; ks < 2; ++ks) {
        af[i][ks] = *reinterpret_cast<const s16x8*>(&As[(wm * 64 + i * 16 + lr) * 64 + ks * 32 + lg * 8]);
        bf[i][ks] = *reinterpret_cast<const s16x8*>(&Bs[(wn * 64 + i * 16 + lr) * 64 + ks * 32 + lg * 8]);
      }
    }
#pragma unroll
    for (int mf = 0; mf < 4; ++mf)
#pragma unroll
      for (int nf = 0; nf < 4; ++nf) {
        acc[mf][nf] = __builtin_amdgcn_mfma_f32_16x16x32_bf16(af[mf][0], bf[nf][0], acc[mf][nf], 0, 0, 0);
        acc[mf][nf] = __builtin_amdgcn_mfma_f32_16x16x32_bf16(af[mf][1], bf[nf][1], acc[mf][nf], 0, 0, 0);
      }
    __syncthreads();
  }

#pragma unroll
  for (int nf = 0; nf < 4; ++nf) {
    const int ng = n0 + wn * 64 + nf * 16 + lr;
    const float bias = bo[ng];
#pragma unroll
    for (int mf = 0; mf < 4; ++mf) {
      const int mg = m0 + wm * 64 + mf * 16 + lg * 4;
#pragma unroll
      for (int r = 0; r < 4; ++r)
        out[(size_t)(mg + r) * Ec + ng] = acc[mf][nf][r] + bias;
    }
  }
}

// ---------------- local attention (swapped-QK, per-lane softmax) ----------------
// One wave per block (64 thr), 6144 blocks, XCD-swizzled: each XCD owns 3 bh
// slices (K+V 3 MB -> L2). QK computed as mfma(K,Q): lane holds 16 scores of
// query q=lr -> softmax = in-lane reduce + 2 shfls. P repacked via
// v_cvt_pk_bf16_f32 + 4x ds_write_b64, read back as PV A-fragments.
// NOTE: no min-waves launch-bounds arg — round 3's (64,4) capped VGPR at 64
// and spilled the ~150-reg working set to scratch (512 MB WRITE_SIZE).
__global__ __launch_bounds__(64) void k_attn(
    const u16* __restrict__ q_ws, const u16* __restrict__ k_ws,
    const u16* __restrict__ vt_ws, u16* __restrict__ ctx_ws) {
  __shared__ __align__(16) u16 P[16 * 72]; // stride 72 u16 = 144 B (16B-aligned rows, ~2-way banks)
  const int lin = blockIdx.x;
  const int work = (lin & 7) * 768 + (lin >> 3); // bijective XCD swizzle (6144 % 8 == 0)
  const int bh = work >> 8;
  const int chunk = (work >> 2) & 63;
  const int w = work & 3;
  const int b = bh / Hc, h = bh - b * Hc;
  const int lane = threadIdx.x & 63;
  const int lr = lane & 15, lg = lane >> 4;

  const u16* qb = q_ws + (size_t)bh * Sc * 64;
  const u16* kb = k_ws + (size_t)bh * Sc * 64;
  const u16* vb = vt_ws + (size_t)bh * 64 * Sc;

  // Q as B-fragment: n = query = lr
  const int qrow = chunk * 64 + w * 16 + lr;
  const s16x8 qf0 = *reinterpret_cast<const s16x8*>(&qb[(size_t)qrow * 64 + lg * 8]);
  const s16x8 qf1 = *reinterpret_cast<const s16x8*>(&qb[(size_t)qrow * 64 + 32 + lg * 8]);

  float mrow = -3e38f;  // running max of query lr
  float ssum = 0.f;     // per-lane partial denominator (this lane's key subset)
  f32x4 ctx[4] = {};

  const int t0 = chunk < 4 ? 4 - chunk : 0;
  const int t1 = chunk > 59 ? 68 - chunk : 9;

  auto loadK = [&](s16x8 (&kf)[4][2], int t) {
    const int key0 = (chunk - 4 + t) * 64;
#pragma unroll
    for (int nt = 0; nt < 4; ++nt) {
      const u16* kp = &kb[(size_t)(key0 + nt * 16 + lr) * 64 + lg * 8];
      kf[nt][0] = *reinterpret_cast<const s16x8*>(kp);
      kf[nt][1] = *reinterpret_cast<const s16x8*>(kp + 32);
    }
  };

  auto step = [&](s16x8 (&kf)[4][2], s16x8 (&kn)[4][2], int t) {
    const int key0 = (chunk - 4 + t) * 64;
    // S^T = K Q^T: sv[nt][r] = S[key=nt*16+lg*4+r][query=lr]
    f32x4 sv[4];
    __builtin_amdgcn_s_setprio(1);
#pragma unroll
    for (int nt = 0; nt < 4; ++nt) {
      f32x4 z = {};
      z = __builtin_amdgcn_mfma_f32_16x16x32_bf16(kf[nt][0], qf0, z, 0, 0, 0);
      z = __builtin_amdgcn_mfma_f32_16x16x32_bf16(kf[nt][1], qf1, z, 0, 0, 0);
      sv[nt] = z;
    }
    __builtin_amdgcn_s_setprio(0);
    // prefetch next K tile (hidden under softmax+PV)
    if (t + 1 < t1) loadK(kn, t + 1);
    // issue V loads now; latency hides under the softmax chain
    s16x8 vf[4][2];
#pragma unroll
    for (int nt = 0; nt < 4; ++nt) {
      const u16* vp = &vb[(size_t)(nt * 16 + lr) * Sc + key0 + lg * 8];
      vf[nt][0] = *reinterpret_cast<const s16x8*>(vp);
      vf[nt][1] = *reinterpret_cast<const s16x8*>(vp + 32);
    }
    // ---- per-lane softmax for query lr ----
    float pm;
    {
      f32x4 m4 = sv[0];
      m4 = {fmaxf(m4[0], sv[1][0]), fmaxf(m4[1], sv[1][1]), fmaxf(m4[2], sv[1][2]), fmaxf(m4[3], sv[1][3])};
      m4 = {fmaxf(m4[0], sv[2][0]), fmaxf(m4[1], sv[2][1]), fmaxf(m4[2], sv[2][2]), fmaxf(m4[3], sv[2][3])};
      m4 = {fmaxf(m4[0], sv[3][0]), fmaxf(m4[1], sv[3][1]), fmaxf(m4[2], sv[3][2]), fmaxf(m4[3], sv[3][3])};
      pm = fmaxf(fmaxf(m4[0], m4[1]), fmaxf(m4[2], m4[3]));
    }
    pm = fmaxf(pm, __shfl_xor(pm, 16));
    pm = fmaxf(pm, __shfl_xor(pm, 32));
    // defer-max (T13): skip rescale while tile max stays within THR of running max
    if (!__all(pm <= mrow + 5.0f)) {
      const float mn = fmaxf(mrow, pm);
      const float scl = exp2f((mrow - mn) * LOG2E);
      ssum *= scl;
      float sc[4];
#pragma unroll
      for (int r = 0; r < 4; ++r) sc[r] = __shfl(scl, (lg << 2) | r); // ctx query = lg*4+r
#pragma unroll
      for (int nt = 0; nt < 4; ++nt)
#pragma unroll
        for (int r = 0; r < 4; ++r) ctx[nt][r] *= sc[r];
      mrow = mn;
    }
    const float ml2e = mrow * LOG2E;
    float ps = 0.f;
    uint32_t pk[4][2];
#pragma unroll
    for (int nt = 0; nt < 4; ++nt) {
      const float p0 = exp2f(sv[nt][0] * LOG2E - ml2e);
      const float p1 = exp2f(sv[nt][1] * LOG2E - ml2e);
      const float p2 = exp2f(sv[nt][2] * LOG2E - ml2e);
      const float p3 = exp2f(sv[nt][3] * LOG2E - ml2e);
      ps += (p0 + p1) + (p2 + p3);
      asm("v_cvt_pk_bf16_f32 %0, %1, %2" : "=v"(pk[nt][0]) : "v"(p0), "v"(p1));
      asm("v_cvt_pk_bf16_f32 %0, %1, %2" : "=v"(pk[nt][1]) : "v"(p2), "v"(p3));
    }
    ssum += ps;
    // P[q=lr][key]: 4 consecutive u16 per (nt) -> b64 writes
#pragma unroll
    for (int nt = 0; nt < 4; ++nt) {
      uint2 d; d.x = pk[nt][0]; d.y = pk[nt][1];
      *reinterpret_cast<uint2*>(&P[lr * 72 + nt * 16 + lg * 4]) = d;
    }
    // wave-local write->read ordering (guide rule #18)
    asm volatile("s_waitcnt lgkmcnt(0)" ::: "memory");
    __builtin_amdgcn_sched_barrier(0);
    // PV A-fragment: A[m=q=lr][k=key=lg*8..+7]
    const s16x8 pa0 = *reinterpret_cast<const s16x8*>(&P[lr * 72 + lg * 8]);
    const s16x8 pa1 = *reinterpret_cast<const s16x8*>(&P[lr * 72 + 32 + lg * 8]);
    __builtin_amdgcn_s_setprio(1);
#pragma unroll
    for (int nt = 0; nt < 4; ++nt) {
      ctx[nt] = __builtin_amdgcn_mfma_f32_16x16x32_bf16(pa0, vf[nt][0], ctx[nt], 0, 0, 0);
      ctx[nt] = __builtin_amdgcn_mfma_f32_16x16x32_bf16(pa1, vf[nt][1], ctx[nt], 0, 0, 0);
    }
    __builtin_amdgcn_s_setprio(0);
  };

  s16x8 kfA[4][2], kfB[4][2];
  loadK(kfA, t0);
  for (int t = t0; t < t1; ++t) {
    if (((t - t0) & 1) == 0) step(kfA, kfB, t); // uniform parity -> static reg indexing
    else step(kfB, kfA, t);
  }

  // finish denominator: sum per-lane partials across the 4 lg copies of query lr
  float s = ssum;
  s += __shfl_xor(s, 16);
  s += __shfl_xor(s, 32);
  const float invq = 1.f / s;
  float ic[4];
#pragma unroll
  for (int r = 0; r < 4; ++r) ic[r] = __shfl(invq, (lg << 2) | r); // ctx query = lg*4+r

  const int tok = chunk * 64 + w * 16 + lg * 4;
#pragma unroll
  for (int nt = 0; nt < 4; ++nt) {
    const int col = h * 64 + nt * 16 + lr;
#pragma unroll
    for (int r = 0; r < 4; ++r)
      ctx_ws[(size_t)(b * Sc + tok + r) * Ec + col] = f2b(ctx[nt][r] * ic[r]);
  }
}

extern "C" void kernel_launch(void* const* d_in, const int* in_sizes, int n_in,
                              void* d_out, int out_size, void* d_ws, size_t ws_size,
                              hipStream_t stream) {
  const float* hs = (const float*)d_in[0];
  const float* Wq = (const float*)d_in[1];
  const float* bq = (const float*)d_in[2];
  const float* Wk = (const float*)d_in[3];
  const float* bk = (const float*)d_in[4];
  const float* Wv = (const float*)d_in[5];
  const float* bv = (const float*)d_in[6];
  const float* Wo = (const float*)d_in[7];
  const float* bo = (const float*)d_in[8];
  float* out = (float*)d_out;

  char* ws = (char*)d_ws;
  size_t o = 0;
  u16* hsb = (u16*)(ws + o);   o += (size_t)Mrows * Ec * 2;
  u16* wqkvt = (u16*)(ws + o); o += (size_t)3 * Ec * Ec * 2;
  u16* wot = (u16*)(ws + o);   o += (size_t)Ec * Ec * 2;
  u16* q_ws = (u16*)(ws + o);  o += (size_t)Mrows * Ec * 2;      // [b,h,s,d]
  u16* k_ws = (u16*)(ws + o);  o += (size_t)Mrows * Ec * 2;      // [b,h,s,d]
  u16* vt_ws = (u16*)(ws + o); o += (size_t)Mrows * Ec * 2;      // [b,h,d,s]
  u16* ctx_ws = (u16*)(ws + o); o += (size_t)Mrows * Ec * 2;     // [b*s, e]

  const int nhs = Mrows * Ec;
  k_cvt<<<nhs / (256 * 4), 256, 0, stream>>>(hs, hsb, nhs);
  dim3 tb(32, 8);
  dim3 tg(Ec / 32, Ec / 32);
  k_tcvt<<<tg, tb, 0, stream>>>(Wq, wqkvt, Ec, Ec);
  k_tcvt<<<tg, tb, 0, stream>>>(Wk, wqkvt + (size_t)Ec * Ec, Ec, Ec);
  k_tcvt<<<tg, tb, 0, stream>>>(Wv, wqkvt + (size_t)2 * Ec * Ec, Ec, Ec);
  k_tcvt<<<tg, tb, 0, stream>>>(Wo, wot, Ec, Ec);

  k_gemm_qkv<<<1152, 256, 0, stream>>>(hsb, wqkvt, bq, bk, bv, q_ws, k_ws, vt_ws);

  k_attn<<<6144, 64, 0, stream>>>(q_ws, k_ws, vt_ws, ctx_ws);

  k_gemm_out<<<384, 256, 0, stream>>>(ctx_ws, wot, bo, out);
}

// Round 5
// 143.311 us; speedup vs baseline: 2.1780x; 1.4276x over previous
//
#include <hip/hip_runtime.h>
#include <stdint.h>

typedef unsigned short u16;
typedef short s16x8 __attribute__((ext_vector_type(8)));
typedef float f32x4 __attribute__((ext_vector_type(4)));

#define LOG2E 1.44269504088896340736f

constexpr int Bc = 2, Sc = 4096, Ec = 768, Hc = 12;
constexpr int Mrows = Bc * Sc; // 8192

__device__ __forceinline__ u16 f2b(float x) {
  union { float f; uint32_t u; } v; v.f = x;
  return (u16)((v.u + 0x7FFFu + ((v.u >> 16) & 1u)) >> 16);
}

__device__ __forceinline__ void gld16(const u16* g, u16* l) {
  __builtin_amdgcn_global_load_lds(
      (const __attribute__((address_space(1))) void*)g,
      (__attribute__((address_space(3))) void*)l,
      16, 0, 0);
}

// ---------------- convert hs f32 -> bf16 ----------------
__global__ void k_cvt(const float* __restrict__ in, u16* __restrict__ out, int n) {
  int i = (blockIdx.x * blockDim.x + threadIdx.x) * 4;
  if (i >= n) return;
  const float4 v = *reinterpret_cast<const float4*>(in + i);
  ushort4 o;
  o.x = f2b(v.x); o.y = f2b(v.y); o.z = f2b(v.z); o.w = f2b(v.w);
  *reinterpret_cast<ushort4*>(out + i) = o;
}

// ---------------- transpose + convert: out[c][r] = bf16(in[r][c]) ----------------
__global__ void k_tcvt(const float* __restrict__ in, u16* __restrict__ out, int RR, int CC) {
  __shared__ float t[32][33];
  const int c0 = blockIdx.x * 32, r0 = blockIdx.y * 32;
  const int tx = threadIdx.x, ty = threadIdx.y;
#pragma unroll
  for (int i = 0; i < 32; i += 8)
    t[ty + i][tx] = in[(size_t)(r0 + ty + i) * CC + c0 + tx];
  __syncthreads();
#pragma unroll
  for (int i = 0; i < 32; i += 8)
    out[(size_t)(c0 + ty + i) * RR + r0 + tx] = f2b(t[tx][ty + i]);
}

// ---------------- QKV GEMM: A[8192x768] @ Bt[2304x768]^T, scatter epilogue ----------------
__global__ __launch_bounds__(256) void k_gemm_qkv(
    const u16* __restrict__ A, const u16* __restrict__ Bt,
    const float* __restrict__ bq, const float* __restrict__ bk, const float* __restrict__ bv,
    u16* __restrict__ q_ws, u16* __restrict__ k_ws, u16* __restrict__ vt_ws) {
  __shared__ __align__(16) u16 As[128 * 64];
  __shared__ __align__(16) u16 Bs[128 * 64];
  const int bid = blockIdx.x;
  const int xcd = bid & 7, ii = bid >> 3;          // ii in 0..143
  const int m0 = (xcd * 8 + (ii & 7)) * 128;       // 64 M-tiles
  const int n0 = (ii >> 3) * 128;                  // 18 N-tiles
  const int tid = threadIdx.x;
  const int lane = tid & 63, w = tid >> 6;
  const int wm = w >> 1, wn = w & 1;
  const int lr = lane & 15, lg = lane >> 4;

  f32x4 acc[4][4] = {};
  const int fl0 = lane * 8;

  for (int k0 = 0; k0 < Ec; k0 += 64) {
#pragma unroll
    for (int c = 0; c < 4; ++c) {
      const int f = (w * 4 + c) * 512;
      const int fl = f + fl0;
      const int row = fl >> 6, col = fl & 63;
      gld16(A + (size_t)(m0 + row) * Ec + k0 + col, &As[f]);
      gld16(Bt + (size_t)(n0 + row) * Ec + k0 + col, &Bs[f]);
    }
    __syncthreads();
    s16x8 af[4][2], bf[4][2];
#pragma unroll
    for (int i = 0; i < 4; ++i) {
#pragma unroll
      for (int ks = 0; ks < 2; ++ks) {
        af[i][ks] = *reinterpret_cast<const s16x8*>(&As[(wm * 64 + i * 16 + lr) * 64 + ks * 32 + lg * 8]);
        bf[i][ks] = *reinterpret_cast<const s16x8*>(&Bs[(wn * 64 + i * 16 + lr) * 64 + ks * 32 + lg * 8]);
      }
    }
#pragma unroll
    for (int mf = 0; mf < 4; ++mf)
#pragma unroll
      for (int nf = 0; nf < 4; ++nf) {
        acc[mf][nf] = __builtin_amdgcn_mfma_f32_16x16x32_bf16(af[mf][0], bf[nf][0], acc[mf][nf], 0, 0, 0);
        acc[mf][nf] = __builtin_amdgcn_mfma_f32_16x16x32_bf16(af[mf][1], bf[nf][1], acc[mf][nf], 0, 0, 0);
      }
    __syncthreads();
  }

  const int which = n0 / Ec; // 0=q 1=k 2=v, uniform per block
#pragma unroll
  for (int nf = 0; nf < 4; ++nf) {
    const int ng = n0 + wn * 64 + nf * 16 + lr;
    const int nl = ng - which * Ec;
    const int hh = nl >> 6, dd = nl & 63;
    const float bias = (which == 0 ? bq[nl] : which == 1 ? bk[nl] : bv[nl]);
#pragma unroll
    for (int mf = 0; mf < 4; ++mf) {
      const int mg = m0 + wm * 64 + mf * 16 + lg * 4;
      const int bb = mg >> 12, ss = mg & (Sc - 1);
      const int bh = bb * Hc + hh;
      if (which == 2) {
        ushort4 pk;
        pk.x = f2b(acc[mf][nf][0] + bias);
        pk.y = f2b(acc[mf][nf][1] + bias);
        pk.z = f2b(acc[mf][nf][2] + bias);
        pk.w = f2b(acc[mf][nf][3] + bias);
        *reinterpret_cast<ushort4*>(&vt_ws[((size_t)bh * 64 + dd) * Sc + ss]) = pk;
      } else {
        u16* dst = (which == 0) ? q_ws : k_ws;
        const float scl = (which == 0) ? 0.125f : 1.0f;
#pragma unroll
        for (int r = 0; r < 4; ++r)
          dst[((size_t)bh * Sc + ss + r) * 64 + dd] = f2b((acc[mf][nf][r] + bias) * scl);
      }
    }
  }
}

// ---------------- output GEMM: ctx[8192x768] @ Wo^T[768x768], +bo, f32 out ----------------
__global__ __launch_bounds__(256) void k_gemm_out(
    const u16* __restrict__ A, const u16* __restrict__ Bt,
    const float* __restrict__ bo, float* __restrict__ out) {
  __shared__ __align__(16) u16 As[128 * 64];
  __shared__ __align__(16) u16 Bs[128 * 64];
  const int bid = blockIdx.x;
  const int xcd = bid & 7, ii = bid >> 3;          // ii in 0..47
  const int m0 = (xcd * 8 + (ii & 7)) * 128;
  const int n0 = (ii >> 3) * 128;                  // 6 N-tiles
  const int tid = threadIdx.x;
  const int lane = tid & 63, w = tid >> 6;
  const int wm = w >> 1, wn = w & 1;
  const int lr = lane & 15, lg = lane >> 4;

  f32x4 acc[4][4] = {};
  const int fl0 = lane * 8;

  for (int k0 = 0; k0 < Ec; k0 += 64) {
#pragma unroll
    for (int c = 0; c < 4; ++c) {
      const int f = (w * 4 + c) * 512;
      const int fl = f + fl0;
      const int row = fl >> 6, col = fl & 63;
      gld16(A + (size_t)(m0 + row) * Ec + k0 + col, &As[f]);
      gld16(Bt + (size_t)(n0 + row) * Ec + k0 + col, &Bs[f]);
    }
    __syncthreads();
    s16x8 af[4][2], bf[4][2];
#pragma unroll
    for (int i = 0; i < 4; ++i) {
#pragma unroll
      for (int ks = 0; ks < 2; ++ks) {
        af[i][ks] = *reinterpret_cast<const s16x8*>(&As[(wm * 64 + i * 16 + lr) * 64 + ks * 32 + lg * 8]);
        bf[i][ks] = *reinterpret_cast<const s16x8*>(&Bs[(wn * 64 + i * 16 + lr) * 64 + ks * 32 + lg * 8]);
      }
    }
#pragma unroll
    for (int mf = 0; mf < 4; ++mf)
#pragma unroll
      for (int nf = 0; nf < 4; ++nf) {
        acc[mf][nf] = __builtin_amdgcn_mfma_f32_16x16x32_bf16(af[mf][0], bf[nf][0], acc[mf][nf], 0, 0, 0);
        acc[mf][nf] = __builtin_amdgcn_mfma_f32_16x16x32_bf16(af[mf][1], bf[nf][1], acc[mf][nf], 0, 0, 0);
      }
    __syncthreads();
  }

#pragma unroll
  for (int nf = 0; nf < 4; ++nf) {
    const int ng = n0 + wn * 64 + nf * 16 + lr;
    const float bias = bo[ng];
#pragma unroll
    for (int mf = 0; mf < 4; ++mf) {
      const int mg = m0 + wm * 64 + mf * 16 + lg * 4;
#pragma unroll
      for (int r = 0; r < 4; ++r)
        out[(size_t)(mg + r) * Ec + ng] = acc[mf][nf][r] + bias;
    }
  }
}

// ---------------- local attention (LDS-staged K/V, swapped-QK softmax) ----------------
// Block = 4 waves, one (chunk, bh); 1536 blocks XCD-swizzled (3 bh slices/XCD).
// K/V tiles staged ONCE per block via global_load_lds (zero VGPR cost, 4x less
// L2 traffic than per-wave register staging), double-buffered with raw
// s_barrier + counted vmcnt(4) so next-tile staging stays in flight across the
// barrier. Fragments via ds_read_b128 with XOR swizzle (T2): gld_lds writes
// linearly, so the swizzle is applied as inverse-permuted GLOBAL source +
// same-permuted LDS read (rule #21). Softmax: swapped-QK per-lane (round 4).
__global__ __launch_bounds__(256) void k_attn(
    const u16* __restrict__ q_ws, const u16* __restrict__ k_ws,
    const u16* __restrict__ vt_ws, u16* __restrict__ ctx_ws) {
  __shared__ __align__(16) u16 Kb[2][64 * 64]; // [key][d], 8 KB each
  __shared__ __align__(16) u16 Vb[2][64 * 64]; // [d][key], 8 KB each
  __shared__ __align__(16) u16 P[4][16 * 72];  // per-wave P, stride 72
  const int lin = blockIdx.x;
  const int work = (lin & 7) * 192 + (lin >> 3); // bijective (1536 % 8 == 0)
  const int chunk = work & 63;
  const int bh = work >> 6;
  const int b = bh / Hc, h = bh - b * Hc;
  const int tid = threadIdx.x;
  const int lane = tid & 63, w = tid >> 6;
  const int lr = lane & 15, lg = lane >> 4;

  const u16* qb = q_ws + (size_t)bh * Sc * 64;
  const u16* kb = k_ws + (size_t)bh * Sc * 64;
  const u16* vb = vt_ws + (size_t)bh * 64 * Sc;

  // Q as B-fragment: n = query = lr (wave w owns queries w*16..w*16+15)
  const int qrow = chunk * 64 + w * 16 + lr;
  const s16x8 qf0 = *reinterpret_cast<const s16x8*>(&qb[(size_t)qrow * 64 + lg * 8]);
  const s16x8 qf1 = *reinterpret_cast<const s16x8*>(&qb[(size_t)qrow * 64 + 32 + lg * 8]);

  float mrow = -3e38f;
  float ssum = 0.f;
  f32x4 ctx[4] = {};

  const int t0 = chunk < 4 ? 4 - chunk : 0;
  const int t1 = chunk > 59 ? 68 - chunk : 9;
  u16* pw = &P[w][0];

  // staging: 256 threads x 16B x 2 rounds per 8KB tile. LDS dest linear
  // (wave base + lane*16); global source carries the inverse XOR swizzle.
  const int srow = lane >> 3; // 0..7 within the wave's 8-row slab
  const int u8 = lane & 7;

  auto stage = [&](int p, int t) {
    const int key0 = (chunk - 4 + t) * 64;
#pragma unroll
    for (int r2 = 0; r2 < 2; ++r2) {
      const int row = w * 8 + r2 * 32 + srow;
      const int sw = ((u8 ^ (row & 7)) << 3);
      const int ldsbase = (w * 8 + r2 * 32) * 64; // wave-uniform
      gld16(kb + (size_t)(key0 + row) * 64 + sw, &Kb[p][ldsbase]);
      gld16(vb + (size_t)row * Sc + key0 + sw, &Vb[p][ldsbase]);
    }
  };

  auto compute = [&](int p, int t) {
    const int key0 = (chunk - 4 + t) * 64;
    (void)key0;
    const u16* kt = &Kb[p][0];
    const u16* vt = &Vb[p][0];
    // K fragments (A-operand of swapped QK): A[m=key][k=d]
    s16x8 kf[4][2];
#pragma unroll
    for (int nt = 0; nt < 4; ++nt) {
      const int row = nt * 16 + lr;
      const int x = row & 7;
#pragma unroll
      for (int ks = 0; ks < 2; ++ks) {
        const int c = ((ks * 4 + lg) ^ x) << 3;
        kf[nt][ks] = *reinterpret_cast<const s16x8*>(&kt[row * 64 + c]);
      }
    }
    // S^T = K Q^T: sv[nt][r] = S[key=nt*16+lg*4+r][query=lr]
    f32x4 sv[4];
    __builtin_amdgcn_s_setprio(1);
#pragma unroll
    for (int nt = 0; nt < 4; ++nt) {
      f32x4 z = {};
      z = __builtin_amdgcn_mfma_f32_16x16x32_bf16(kf[nt][0], qf0, z, 0, 0, 0);
      z = __builtin_amdgcn_mfma_f32_16x16x32_bf16(kf[nt][1], qf1, z, 0, 0, 0);
      sv[nt] = z;
    }
    __builtin_amdgcn_s_setprio(0);
    // V fragments (B-operand of PV): B[n=d][k=key]; latency hides under softmax
    s16x8 vf[4][2];
#pragma unroll
    for (int nt = 0; nt < 4; ++nt) {
      const int row = nt * 16 + lr;
      const int x = row & 7;
#pragma unroll
      for (int ks = 0; ks < 2; ++ks) {
        const int c = ((ks * 4 + lg) ^ x) << 3;
        vf[nt][ks] = *reinterpret_cast<const s16x8*>(&vt[row * 64 + c]);
      }
    }
    // ---- per-lane softmax for query lr ----
    float pm;
    {
      f32x4 m4 = sv[0];
      m4 = {fmaxf(m4[0], sv[1][0]), fmaxf(m4[1], sv[1][1]), fmaxf(m4[2], sv[1][2]), fmaxf(m4[3], sv[1][3])};
      m4 = {fmaxf(m4[0], sv[2][0]), fmaxf(m4[1], sv[2][1]), fmaxf(m4[2], sv[2][2]), fmaxf(m4[3], sv[2][3])};
      m4 = {fmaxf(m4[0], sv[3][0]), fmaxf(m4[1], sv[3][1]), fmaxf(m4[2], sv[3][2]), fmaxf(m4[3], sv[3][3])};
      pm = fmaxf(fmaxf(m4[0], m4[1]), fmaxf(m4[2], m4[3]));
    }
    pm = fmaxf(pm, __shfl_xor(pm, 16));
    pm = fmaxf(pm, __shfl_xor(pm, 32));
    // defer-max (T13)
    if (!__all(pm <= mrow + 5.0f)) {
      const float mn = fmaxf(mrow, pm);
      const float scl = exp2f((mrow - mn) * LOG2E);
      ssum *= scl;
      float sc[4];
#pragma unroll
      for (int r = 0; r < 4; ++r) sc[r] = __shfl(scl, (lg << 2) | r);
#pragma unroll
      for (int nt = 0; nt < 4; ++nt)
#pragma unroll
        for (int r = 0; r < 4; ++r) ctx[nt][r] *= sc[r];
      mrow = mn;
    }
    const float ml2e = mrow * LOG2E;
    float ps = 0.f;
    uint32_t pk[4][2];
#pragma unroll
    for (int nt = 0; nt < 4; ++nt) {
      const float p0 = exp2f(sv[nt][0] * LOG2E - ml2e);
      const float p1 = exp2f(sv[nt][1] * LOG2E - ml2e);
      const float p2 = exp2f(sv[nt][2] * LOG2E - ml2e);
      const float p3 = exp2f(sv[nt][3] * LOG2E - ml2e);
      ps += (p0 + p1) + (p2 + p3);
      asm("v_cvt_pk_bf16_f32 %0, %1, %2" : "=v"(pk[nt][0]) : "v"(p0), "v"(p1));
      asm("v_cvt_pk_bf16_f32 %0, %1, %2" : "=v"(pk[nt][1]) : "v"(p2), "v"(p3));
    }
    ssum += ps;
#pragma unroll
    for (int nt = 0; nt < 4; ++nt) {
      uint2 d; d.x = pk[nt][0]; d.y = pk[nt][1];
      *reinterpret_cast<uint2*>(&pw[lr * 72 + nt * 16 + lg * 4]) = d;
    }
    // wave-local P write->read ordering (rule #18)
    asm volatile("s_waitcnt lgkmcnt(0)" ::: "memory");
    __builtin_amdgcn_sched_barrier(0);
    const s16x8 pa0 = *reinterpret_cast<const s16x8*>(&pw[lr * 72 + lg * 8]);
    const s16x8 pa1 = *reinterpret_cast<const s16x8*>(&pw[lr * 72 + 32 + lg * 8]);
    __builtin_amdgcn_s_setprio(1);
#pragma unroll
    for (int nt = 0; nt < 4; ++nt) {
      ctx[nt] = __builtin_amdgcn_mfma_f32_16x16x32_bf16(pa0, vf[nt][0], ctx[nt], 0, 0, 0);
      ctx[nt] = __builtin_amdgcn_mfma_f32_16x16x32_bf16(pa1, vf[nt][1], ctx[nt], 0, 0, 0);
    }
    __builtin_amdgcn_s_setprio(0);
  };

  // ---- main loop: double-buffered, counted vmcnt, raw barriers ----
  int p = 0;
  stage(0, t0);
  for (int t = t0; t < t1; ++t) {
    // barrier A: all waves' reads of buf[p^1] (prev iter) are retired
    // (every ds_read is consumed by an MFMA before the wave arrives here)
    __builtin_amdgcn_s_barrier();
    if (t + 1 < t1) {
      stage(p ^ 1, t + 1);
      asm volatile("s_waitcnt vmcnt(4)" ::: "memory"); // oldest 4 = buf[p] staging done
    } else {
      asm volatile("s_waitcnt vmcnt(0)" ::: "memory");
    }
    // barrier B: every wave has retired its buf[p] staging loads
    __builtin_amdgcn_s_barrier();
    compute(p, t);
    p ^= 1;
  }

  // finish denominator across the 4 lg copies of query lr
  float s = ssum;
  s += __shfl_xor(s, 16);
  s += __shfl_xor(s, 32);
  const float invq = 1.f / s;
  float ic[4];
#pragma unroll
  for (int r = 0; r < 4; ++r) ic[r] = __shfl(invq, (lg << 2) | r);

  const int tok = chunk * 64 + w * 16 + lg * 4;
#pragma unroll
  for (int nt = 0; nt < 4; ++nt) {
    const int col = h * 64 + nt * 16 + lr;
#pragma unroll
    for (int r = 0; r < 4; ++r)
      ctx_ws[(size_t)(b * Sc + tok + r) * Ec + col] = f2b(ctx[nt][r] * ic[r]);
  }
}

extern "C" void kernel_launch(void* const* d_in, const int* in_sizes, int n_in,
                              void* d_out, int out_size, void* d_ws, size_t ws_size,
                              hipStream_t stream) {
  const float* hs = (const float*)d_in[0];
  const float* Wq = (const float*)d_in[1];
  const float* bq = (const float*)d_in[2];
  const float* Wk = (const float*)d_in[3];
  const float* bk = (const float*)d_in[4];
  const float* Wv = (const float*)d_in[5];
  const float* bv = (const float*)d_in[6];
  const float* Wo = (const float*)d_in[7];
  const float* bo = (const float*)d_in[8];
  float* out = (float*)d_out;

  char* ws = (char*)d_ws;
  size_t o = 0;
  u16* hsb = (u16*)(ws + o);   o += (size_t)Mrows * Ec * 2;
  u16* wqkvt = (u16*)(ws + o); o += (size_t)3 * Ec * Ec * 2;
  u16* wot = (u16*)(ws + o);   o += (size_t)Ec * Ec * 2;
  u16* q_ws = (u16*)(ws + o);  o += (size_t)Mrows * Ec * 2;      // [b,h,s,d]
  u16* k_ws = (u16*)(ws + o);  o += (size_t)Mrows * Ec * 2;      // [b,h,s,d]
  u16* vt_ws = (u16*)(ws + o); o += (size_t)Mrows * Ec * 2;      // [b,h,d,s]
  u16* ctx_ws = (u16*)(ws + o); o += (size_t)Mrows * Ec * 2;     // [b*s, e]

  const int nhs = Mrows * Ec;
  k_cvt<<<nhs / (256 * 4), 256, 0, stream>>>(hs, hsb, nhs);
  dim3 tb(32, 8);
  dim3 tg(Ec / 32, Ec / 32);
  k_tcvt<<<tg, tb, 0, stream>>>(Wq, wqkvt, Ec, Ec);
  k_tcvt<<<tg, tb, 0, stream>>>(Wk, wqkvt + (size_t)Ec * Ec, Ec, Ec);
  k_tcvt<<<tg, tb, 0, stream>>>(Wv, wqkvt + (size_t)2 * Ec * Ec, Ec, Ec);
  k_tcvt<<<tg, tb, 0, stream>>>(Wo, wot, Ec, Ec);

  k_gemm_qkv<<<1152, 256, 0, stream>>>(hsb, wqkvt, bq, bk, bv, q_ws, k_ws, vt_ws);

  k_attn<<<1536, 256, 0, stream>>>(q_ws, k_ws, vt_ws, ctx_ws);

  k_gemm_out<<<384, 256, 0, stream>>>(ctx_ws, wot, bo, out);
}